// Round 16
// baseline (61.655 us; speedup 1.0000x reference)
//
#include <hip/hip_runtime.h>
#include <hip/hip_bf16.h>

// kernel[i,j] = | prod_{k<16} cos((x[i,k]-y[j,k])/2) |   (f32 in, f32 out)
//
// MFMA formulation (verified r10-r15, absmax 0.00390625): per wire-pair
//   cos(a)cos(b) = 1/2[cos(Rm-Cm) + cos(Rp-Cp)]  -> 4-term separable dot;
// quad (pair x pair) = 16-term dot  Q_q = sum_t A_q[i,t] B_q[j,t];
// out = |Q0 Q1 Q2 Q3|. One mfma_f32_32x32x16_bf16 per quad (K=16 exact).
// Orientation: A=row factors, B=col factors => D lane dim = output column
// (contiguous 128 B store segments); reg r -> row (r&3)+8*(r>>2)+4*(lane>>5)
// [m74/m101, r12-validated numerically].
//
// Tile-shape search closed: r13 64x64 4blk/CU = 60.59 (best);
// r14 128x128 1blk/CU = 61.16; r15 128x64 2blk/CU = 61.43.
// r16 = r13 EXACTLY + packed bf16 cvt (v_cvt_pk_bf16_f32) in staging.
// Budget: total ~60.6 = ~50.3 harness envelope (poison fills) + ~10 kernel;
// kernel floor ~8 (2.7 NT-store drain of 16.8 MB output is hard).

constexpr int D = 16;
constexpr int RSTR = 72;   // LDS row stride in shorts (144 B, 16B-aligned)

typedef short  bf16x8 __attribute__((ext_vector_type(8)));
typedef float  f32x16 __attribute__((ext_vector_type(16)));

static __device__ inline unsigned int pk2(float a, float b) {
    __hip_bfloat162 h = __float22bfloat162_rn(make_float2(a, b));  // lo=a, hi=b
    unsigned int u;
    __builtin_memcpy(&u, &h, 4);
    return u;
}

__global__ __launch_bounds__(256)
void qkern(const float* __restrict__ x, const float* __restrict__ y,
           float* __restrict__ out, int m) {
    __shared__ unsigned short Al[64 * RSTR];   // row terms: 64 rows x 64 bf16
    __shared__ unsigned short Bl[64 * RSTR];   // col terms: 64 cols x 64 bf16

    const int tid   = threadIdx.x;
    const int row0b = blockIdx.x * 64;
    const int col0b = blockIdx.y * 64;

    // ---- Stage: 128 units (64 rows + 64 cols), 2 threads/unit. ----
    {
        const int u    = tid >> 1;
        const int half = tid & 1;
        const bool isrow = (u < 64);
        const float* src = isrow ? (x + (size_t)(row0b + u) * D)
                                 : (y + (size_t)(col0b + (u - 64)) * D);
        unsigned short* dst = (isrow ? Al + (size_t)u * RSTR
                                     : Bl + (size_t)(u - 64) * RSTR);
        const float scale = isrow ? 0.5f : 1.0f;   // 1/2 per pair, rows only

        float f[4][4];
#pragma unroll
        for (int pp = 0; pp < 4; ++pp) {
            const int p = half * 4 + pp;
            const float a0 = src[2 * p], a1 = src[2 * p + 1];
            float sm, cm, sp, cp;
            __sincosf(0.5f * (a0 - a1), &sm, &cm);
            __sincosf(0.5f * (a0 + a1), &sp, &cp);
            f[pp][0] = scale * cm; f[pp][1] = scale * sm;
            f[pp][2] = scale * cp; f[pp][3] = scale * sp;
        }
#pragma unroll
        for (int qq = 0; qq < 2; ++qq) {
            const int q = half * 2 + qq;
            const float* fa = f[2 * qq];
            const float* fb = f[2 * qq + 1];
            uint4 lo, hi;
            lo.x = pk2(fa[0] * fb[0], fa[0] * fb[1]);
            lo.y = pk2(fa[0] * fb[2], fa[0] * fb[3]);
            lo.z = pk2(fa[1] * fb[0], fa[1] * fb[1]);
            lo.w = pk2(fa[1] * fb[2], fa[1] * fb[3]);
            hi.x = pk2(fa[2] * fb[0], fa[2] * fb[1]);
            hi.y = pk2(fa[2] * fb[2], fa[2] * fb[3]);
            hi.z = pk2(fa[3] * fb[0], fa[3] * fb[1]);
            hi.w = pk2(fa[3] * fb[2], fa[3] * fb[3]);
            *(uint4*)(dst + q * 16)     = lo;
            *(uint4*)(dst + q * 16 + 8) = hi;
        }
    }
    __syncthreads();

    // ---- MFMA: wave = one 32x32 quadrant. A=rows, B=cols. ----
    const int wave = tid >> 6;
    const int lane = tid & 63;
    const int l31  = lane & 31;
    const int kh   = lane >> 5;          // k-half
    const int rw   = (wave >> 1) * 32;   // quadrant row base
    const int cw   = (wave & 1) * 32;    // quadrant col base

    const f32x16 zc = {0.f};

    f32x16 prod;
    {
        const bf16x8 a0 = *(const bf16x8*)(Al + (size_t)(rw + l31) * RSTR + kh * 8);
        const bf16x8 b0 = *(const bf16x8*)(Bl + (size_t)(cw + l31) * RSTR + kh * 8);
        prod = __builtin_amdgcn_mfma_f32_32x32x16_bf16(a0, b0, zc, 0, 0, 0);
    }
#pragma unroll
    for (int q = 1; q < 4; ++q) {
        const bf16x8 aq = *(const bf16x8*)(Al + (size_t)(rw + l31) * RSTR + q * 16 + kh * 8);
        const bf16x8 bq = *(const bf16x8*)(Bl + (size_t)(cw + l31) * RSTR + q * 16 + kh * 8);
        const f32x16 acc = __builtin_amdgcn_mfma_f32_32x32x16_bf16(aq, bq, zc, 0, 0, 0);
        prod *= acc;
    }

    // Epilogue: reg r -> row = rw + (r&3)+8*(r>>2)+4*kh; col = cw + l31.
    float* base = out + (size_t)(row0b + rw + 4 * kh) * m + col0b + cw + l31;
#pragma unroll
    for (int r = 0; r < 16; ++r) {
        const int row_off = (r & 3) + 8 * (r >> 2);
        __builtin_nontemporal_store(fabsf(prod[r]), base + (size_t)row_off * m);
    }
}

extern "C" void kernel_launch(void* const* d_in, const int* in_sizes, int n_in,
                              void* d_out, int out_size, void* d_ws, size_t ws_size,
                              hipStream_t stream) {
    const float* x = (const float*)d_in[0];
    const float* y = (const float*)d_in[1];
    float* out = (float*)d_out;
    const int n = in_sizes[0] / D;   // 2048
    const int m = in_sizes[1] / D;   // 2048

    dim3 grid(n / 64, m / 64);       // 32 x 32 = 1024 blocks -> 4 blk/CU
    qkern<<<grid, 256, 0, stream>>>(x, y, out, m);
}

// Round 17
// 60.862 us; speedup vs baseline: 1.0130x; 1.0130x over previous
//
#include <hip/hip_runtime.h>
#include <hip/hip_bf16.h>

// kernel[i,j] = | prod_{k<16} cos((x[i,k]-y[j,k])/2) |   (f32 in, f32 out)
//
// FINAL (r17 = byte-exact revert to r13, the measured best: 60.59 us).
//
// MFMA formulation (verified r10-r16, absmax 0.00390625): per wire-pair
//   cos(a)cos(b) = 1/2[cos(Rm-Cm) + cos(Rp-Cp)]  -> 4-term separable dot;
// quad (pair x pair) = 16-term dot  Q_q = sum_t A_q[i,t] B_q[j,t];
// out = |Q0 Q1 Q2 Q3|. One mfma_f32_32x32x16_bf16 per quad (K=16 exact).
// Orientation: A=row factors, B=col factors => D lane dim = output column
// (contiguous 128 B store segments); reg r -> row (r&3)+8*(r>>2)+4*(lane>>5)
// [m74/m101, r12-validated numerically].
//
// Search closed: tiles 64x64(best)/128x64/128x128; occupancy 1/2/4 blk/CU;
// LDS vs global staging; 16x16x32 vs 32x32x16; operand orientation; NT vs
// plain stores; fused vs split dispatch; pk-cvt (neutral). Budget: ~60.6 us
// total = ~50 us harness envelope (256 MiB poison fill at ~82% HBM peak,
// untouchable) + ~10 us kernel vs ~8 us structural floor (2.7 us = NT drain
// of the 16.8 MB output, hard HBM bound).

constexpr int D = 16;
constexpr int RSTR = 72;   // LDS row stride in shorts (144 B, 16B-aligned)

typedef short  bf16x8 __attribute__((ext_vector_type(8)));
typedef float  f32x16 __attribute__((ext_vector_type(16)));

static __device__ inline unsigned int pk2(float a, float b) {
    __hip_bfloat16 ha = __float2bfloat16(a);
    __hip_bfloat16 hb = __float2bfloat16(b);
    unsigned short ua, ub;
    __builtin_memcpy(&ua, &ha, 2);
    __builtin_memcpy(&ub, &hb, 2);
    return (unsigned int)ua | ((unsigned int)ub << 16);
}

__global__ __launch_bounds__(256)
void qkern(const float* __restrict__ x, const float* __restrict__ y,
           float* __restrict__ out, int m) {
    __shared__ unsigned short Al[64 * RSTR];   // row terms: 64 rows x 64 bf16
    __shared__ unsigned short Bl[64 * RSTR];   // col terms: 64 cols x 64 bf16

    const int tid   = threadIdx.x;
    const int row0b = blockIdx.x * 64;
    const int col0b = blockIdx.y * 64;

    // ---- Stage: 128 units (64 rows + 64 cols), 2 threads/unit. ----
    {
        const int u    = tid >> 1;
        const int half = tid & 1;
        const bool isrow = (u < 64);
        const float* src = isrow ? (x + (size_t)(row0b + u) * D)
                                 : (y + (size_t)(col0b + (u - 64)) * D);
        unsigned short* dst = (isrow ? Al + (size_t)u * RSTR
                                     : Bl + (size_t)(u - 64) * RSTR);
        const float scale = isrow ? 0.5f : 1.0f;   // 1/2 per pair, rows only

        float f[4][4];
#pragma unroll
        for (int pp = 0; pp < 4; ++pp) {
            const int p = half * 4 + pp;
            const float a0 = src[2 * p], a1 = src[2 * p + 1];
            float sm, cm, sp, cp;
            __sincosf(0.5f * (a0 - a1), &sm, &cm);
            __sincosf(0.5f * (a0 + a1), &sp, &cp);
            f[pp][0] = scale * cm; f[pp][1] = scale * sm;
            f[pp][2] = scale * cp; f[pp][3] = scale * sp;
        }
#pragma unroll
        for (int qq = 0; qq < 2; ++qq) {
            const int q = half * 2 + qq;
            const float* fa = f[2 * qq];
            const float* fb = f[2 * qq + 1];
            uint4 lo, hi;
            lo.x = pk2(fa[0] * fb[0], fa[0] * fb[1]);
            lo.y = pk2(fa[0] * fb[2], fa[0] * fb[3]);
            lo.z = pk2(fa[1] * fb[0], fa[1] * fb[1]);
            lo.w = pk2(fa[1] * fb[2], fa[1] * fb[3]);
            hi.x = pk2(fa[2] * fb[0], fa[2] * fb[1]);
            hi.y = pk2(fa[2] * fb[2], fa[2] * fb[3]);
            hi.z = pk2(fa[3] * fb[0], fa[3] * fb[1]);
            hi.w = pk2(fa[3] * fb[2], fa[3] * fb[3]);
            *(uint4*)(dst + q * 16)     = lo;
            *(uint4*)(dst + q * 16 + 8) = hi;
        }
    }
    __syncthreads();

    // ---- MFMA: wave = one 32x32 quadrant. A=rows, B=cols. ----
    const int wave = tid >> 6;
    const int lane = tid & 63;
    const int l31  = lane & 31;
    const int kh   = lane >> 5;          // k-half: 0 -> k0..7, 1 -> k8..15
    const int rw   = (wave >> 1) * 32;   // quadrant row base
    const int cw   = (wave & 1) * 32;    // quadrant col base

    const f32x16 zc = {0.f};

    f32x16 prod;
    {
        const bf16x8 a0 = *(const bf16x8*)(Al + (size_t)(rw + l31) * RSTR + 0 * 16 + kh * 8);
        const bf16x8 b0 = *(const bf16x8*)(Bl + (size_t)(cw + l31) * RSTR + 0 * 16 + kh * 8);
        prod = __builtin_amdgcn_mfma_f32_32x32x16_bf16(a0, b0, zc, 0, 0, 0);
    }
#pragma unroll
    for (int q = 1; q < 4; ++q) {
        const bf16x8 aq = *(const bf16x8*)(Al + (size_t)(rw + l31) * RSTR + q * 16 + kh * 8);
        const bf16x8 bq = *(const bf16x8*)(Bl + (size_t)(cw + l31) * RSTR + q * 16 + kh * 8);
        const f32x16 acc = __builtin_amdgcn_mfma_f32_32x32x16_bf16(aq, bq, zc, 0, 0, 0);
        prod *= acc;
    }

    // Epilogue: reg r -> row = rw + (r&3)+8*(r>>2)+4*kh; col = cw + l31.
    // Lanes walk contiguous cols -> each store = 2 x 128 B full-line segments.
    const int ocol = col0b + cw + l31;
    float* base = out + (size_t)(row0b + rw + 4 * kh) * m + ocol;
#pragma unroll
    for (int r = 0; r < 16; ++r) {
        const int row_off = (r & 3) + 8 * (r >> 2);
        __builtin_nontemporal_store(fabsf(prod[r]), base + (size_t)row_off * m);
    }
}

extern "C" void kernel_launch(void* const* d_in, const int* in_sizes, int n_in,
                              void* d_out, int out_size, void* d_ws, size_t ws_size,
                              hipStream_t stream) {
    const float* x = (const float*)d_in[0];
    const float* y = (const float*)d_in[1];
    float* out = (float*)d_out;
    const int n = in_sizes[0] / D;   // 2048
    const int m = in_sizes[1] / D;   // 2048

    dim3 grid(n / 64, m / 64);       // 32 x 32 = 1024 blocks -> 4 blk/CU
    qkern<<<grid, 256, 0, stream>>>(x, y, out, m);
}